// Round 2
// baseline (81685.638 us; speedup 1.0000x reference)
//
#include <hip/hip_runtime.h>

#define HH    51
#define G4    204        // 4*H
#define T_SEQ 1024
#define T_TOT 1088       // T + future(64)
#define B_TOT 4096
#define MT    16         // batch rows per block
#define NTH   512        // 8 waves
#define WTR   208        // transposed-weight row stride (dwords), lane-consecutive j
#define HS    52         // h row stride (52*4B = 208B, 16B-aligned rows)

// ---- LDS offsets (in floats) ----
#define OFF_WT1 0
#define SZ_WT   (52*WTR)             // 10816
#define OFF_WT2 (OFF_WT1 + SZ_WT)    // W_ih2
#define OFF_WT3 (OFF_WT2 + SZ_WT)    // W_hh2
#define OFF_G   (OFF_WT3 + SZ_WT)    // gates [16][204]
#define OFF_H1  (OFF_G + MT*G4)
#define OFF_H2  (OFF_H1 + MT*HS)
#define OFF_XB  (OFF_H2 + MT*HS)     // x double buffer [2][16][16]
#define OFF_CB1 (OFF_XB + 2*MT*16)
#define OFF_CB2 (OFF_CB1 + 208)
#define OFF_WI1 (OFF_CB2 + 208)
#define OFF_WL  (OFF_WI1 + 208)
#define OFF_XC  (OFF_WL + 64)        // current x per batch row [16]
#define OFF_BL  (OFF_XC + 16)
#define TOT_F   (OFF_BL + 8)         // 38600 floats = 154,400 B

__device__ __forceinline__ float sigm(float v) { return 1.f / (1.f + __expf(-v)); }
__device__ __forceinline__ float tanh_f(float v) { return 1.f - 2.f / (1.f + __expf(2.f * v)); }

// 1 block/CU is forced by the 150.8 KiB LDS block; min-waves=1 lets the
// allocator use up to 256 VGPRs (2 waves/SIMD = our 8 waves/CU) instead of
// spilling the unrolled matvec pipeline to scratch at the 128-VGPR cap.
__launch_bounds__(NTH, 1)
__global__ void lstm_seq_kernel(const float* __restrict__ x,
                                const float* __restrict__ Wih1,
                                const float* __restrict__ Whh1,
                                const float* __restrict__ bih1,
                                const float* __restrict__ bhh1,
                                const float* __restrict__ Wih2,
                                const float* __restrict__ Whh2,
                                const float* __restrict__ bih2,
                                const float* __restrict__ bhh2,
                                const float* __restrict__ Wlin,
                                const float* __restrict__ blin,
                                float* __restrict__ out)
{
  extern __shared__ float sm[];
  const int tid = threadIdx.x;
  const int bg0 = blockIdx.x * MT;

  // zero all LDS (also zero-inits h1/h2 state and all pad columns)
  for (int i = tid; i < TOT_F; i += NTH) sm[i] = 0.f;
  __syncthreads();

  // stage weights transposed: WT[k][j] = W[j][k]; row k=51 stays zero (K-pad)
  for (int i = tid; i < G4 * HH; i += NTH) {
    const int j = i / HH, k = i - j * HH;
    sm[OFF_WT1 + k * WTR + j] = Whh1[i];
    sm[OFF_WT2 + k * WTR + j] = Wih2[i];
    sm[OFF_WT3 + k * WTR + j] = Whh2[i];
  }
  for (int jj = tid; jj < G4; jj += NTH) {
    sm[OFF_CB1 + jj] = bih1[jj] + bhh1[jj];
    sm[OFF_CB2 + jj] = bih2[jj] + bhh2[jj];
    sm[OFF_WI1 + jj] = Wih1[jj];
  }
  if (tid < HH) sm[OFF_WL + tid] = Wlin[tid];
  if (tid == 0) sm[OFF_BL] = blin[0];
  // first x chunk (steps 0..15)
  if (tid < 256) {
    const int b = tid >> 4, tt = tid & 15;
    sm[OFF_XB + b * 16 + tt] = x[(size_t)(bg0 + b) * T_SEQ + tt];
  }
  __syncthreads();
  if (tid < MT) sm[OFF_XC + tid] = sm[OFF_XB + tid * 16];
  __syncthreads();

  // gates-phase mapping: thread -> (gate j, batch half)
  const int j   = tid & 255;
  const bool ja = (j < G4);
  const int bb  = (tid >> 8) * 8;     // batch base: 0 or 8
  // act-phase mapping: wave wv handles batch rows wv and wv+8, lane = hidden k
  const int lane = tid & 63;
  const int wv   = tid >> 6;

  float c1[2] = {0.f, 0.f};
  float c2[2] = {0.f, 0.f};

  for (int t = 0; t < T_TOT; ++t) {
    // prefetch next 16-step x chunk into the other buffer half
    if ((t & 15) == 0) {
      const int nt = t + 16;
      if (nt < T_SEQ && tid < 256) {
        const int b = tid >> 4, tt = tid & 15;
        sm[OFF_XB + (((nt >> 4) & 1) ? 256 : 0) + b * 16 + tt] =
            x[(size_t)(bg0 + b) * T_SEQ + nt + tt];
      }
    }
    // ---- phase A: gates1 = cb1 + Wih1*x + Whh1 @ h1_old ----
    if (ja) {
      float acc[8];
      const float cb = sm[OFF_CB1 + j];
      const float wi = sm[OFF_WI1 + j];
      #pragma unroll
      for (int r = 0; r < 8; ++r) acc[r] = cb + wi * sm[OFF_XC + bb + r];
      #pragma unroll
      for (int c = 0; c < 13; ++c) {
        const float w0 = sm[OFF_WT1 + (4 * c + 0) * WTR + j];
        const float w1 = sm[OFF_WT1 + (4 * c + 1) * WTR + j];
        const float w2 = sm[OFF_WT1 + (4 * c + 2) * WTR + j];
        const float w3 = sm[OFF_WT1 + (4 * c + 3) * WTR + j];
        #pragma unroll
        for (int r = 0; r < 8; ++r) {
          const float4 hv = *reinterpret_cast<const float4*>(&sm[OFF_H1 + (bb + r) * HS + 4 * c]);
          acc[r] += w0 * hv.x + w1 * hv.y + w2 * hv.z + w3 * hv.w;
        }
      }
      #pragma unroll
      for (int r = 0; r < 8; ++r) sm[OFF_G + (bb + r) * G4 + j] = acc[r];
    }
    __syncthreads();
    // ---- phase B: act1 -> h1_new, c1 ----
    #pragma unroll
    for (int p = 0; p < 2; ++p) {
      const int b = wv + 8 * p;
      if (lane < HH) {
        const float gi = sm[OFF_G + b * G4 + lane];
        const float gf = sm[OFF_G + b * G4 + 51 + lane];
        const float gg = sm[OFF_G + b * G4 + 102 + lane];
        const float go = sm[OFF_G + b * G4 + 153 + lane];
        const float cn = sigm(gf) * c1[p] + sigm(gi) * tanh_f(gg);
        c1[p] = cn;
        sm[OFF_H1 + b * HS + lane] = sigm(go) * tanh_f(cn);
      }
    }
    __syncthreads();
    // ---- phase C: gates2 = cb2 + Wih2 @ h1_new + Whh2 @ h2_old ----
    if (ja) {
      float acc[8];
      const float cb = sm[OFF_CB2 + j];
      #pragma unroll
      for (int r = 0; r < 8; ++r) acc[r] = cb;
      #pragma unroll
      for (int c = 0; c < 13; ++c) {
        const float w0 = sm[OFF_WT2 + (4 * c + 0) * WTR + j];
        const float w1 = sm[OFF_WT2 + (4 * c + 1) * WTR + j];
        const float w2 = sm[OFF_WT2 + (4 * c + 2) * WTR + j];
        const float w3 = sm[OFF_WT2 + (4 * c + 3) * WTR + j];
        #pragma unroll
        for (int r = 0; r < 8; ++r) {
          const float4 hv = *reinterpret_cast<const float4*>(&sm[OFF_H1 + (bb + r) * HS + 4 * c]);
          acc[r] += w0 * hv.x + w1 * hv.y + w2 * hv.z + w3 * hv.w;
        }
      }
      #pragma unroll
      for (int c = 0; c < 13; ++c) {
        const float w0 = sm[OFF_WT3 + (4 * c + 0) * WTR + j];
        const float w1 = sm[OFF_WT3 + (4 * c + 1) * WTR + j];
        const float w2 = sm[OFF_WT3 + (4 * c + 2) * WTR + j];
        const float w3 = sm[OFF_WT3 + (4 * c + 3) * WTR + j];
        #pragma unroll
        for (int r = 0; r < 8; ++r) {
          const float4 hv = *reinterpret_cast<const float4*>(&sm[OFF_H2 + (bb + r) * HS + 4 * c]);
          acc[r] += w0 * hv.x + w1 * hv.y + w2 * hv.z + w3 * hv.w;
        }
      }
      #pragma unroll
      for (int r = 0; r < 8; ++r) sm[OFF_G + (bb + r) * G4 + j] = acc[r];
    }
    __syncthreads();
    // ---- phase D: act2 -> h2_new, c2; out = Wlin . h2 + blin; feed xcur ----
    #pragma unroll
    for (int p = 0; p < 2; ++p) {
      const int b = wv + 8 * p;
      float po = 0.f;
      if (lane < HH) {
        const float gi = sm[OFF_G + b * G4 + lane];
        const float gf = sm[OFF_G + b * G4 + 51 + lane];
        const float gg = sm[OFF_G + b * G4 + 102 + lane];
        const float go = sm[OFF_G + b * G4 + 153 + lane];
        const float cn = sigm(gf) * c2[p] + sigm(gi) * tanh_f(gg);
        c2[p] = cn;
        const float hn = sigm(go) * tanh_f(cn);
        sm[OFF_H2 + b * HS + lane] = hn;
        po = sm[OFF_WL + lane] * hn;
      }
      #pragma unroll
      for (int m = 32; m >= 1; m >>= 1) po += __shfl_xor(po, m, 64);
      if (lane == 0) {
        const float ov = po + sm[OFF_BL];
        out[(size_t)(bg0 + b) * T_TOT + t] = ov;
        const int t1 = t + 1;
        float nx;
        if (t1 < T_SEQ) nx = sm[OFF_XB + (((t1 >> 4) & 1) ? 256 : 0) + b * 16 + (t1 & 15)];
        else            nx = ov;   // autoregressive future phase
        sm[OFF_XC + b] = nx;
      }
    }
    __syncthreads();
  }
}

extern "C" void kernel_launch(void* const* d_in, const int* in_sizes, int n_in,
                              void* d_out, int out_size, void* d_ws, size_t ws_size,
                              hipStream_t stream) {
  const float* x    = (const float*)d_in[0];
  const float* Wih1 = (const float*)d_in[1];
  const float* Whh1 = (const float*)d_in[2];
  const float* bih1 = (const float*)d_in[3];
  const float* bhh1 = (const float*)d_in[4];
  const float* Wih2 = (const float*)d_in[5];
  const float* Whh2 = (const float*)d_in[6];
  const float* bih2 = (const float*)d_in[7];
  const float* bhh2 = (const float*)d_in[8];
  const float* Wlin = (const float*)d_in[9];
  const float* blin = (const float*)d_in[10];
  float* out = (float*)d_out;

  const size_t smem = (size_t)TOT_F * sizeof(float);  // ~150.8 KiB, fits 160 KiB LDS
  (void)hipFuncSetAttribute((const void*)lstm_seq_kernel,
                            hipFuncAttributeMaxDynamicSharedMemorySize, (int)smem);

  lstm_seq_kernel<<<B_TOT / MT, NTH, smem, stream>>>(
      x, Wih1, Whh1, bih1, bhh1, Wih2, Whh2, bih2, bhh2, Wlin, blin, out);
}

// Round 3
// 25734.015 us; speedup vs baseline: 3.1742x; 3.1742x over previous
//
#include <hip/hip_runtime.h>

#define HH    51
#define G4    204
#define T_SEQ 1024
#define T_TOT 1088
#define B_TOT 4096
#define MT    16          // batch rows per block (16 rows -> 2 waves x 8)
#define NTH   128         // 2 waves
#define NC    13          // k-chunks of 4 (52 = 4*13, k=51 zero-padded)
#define WMAT  (NC*4*HH*4) // dwords per staged matrix = 10608
#define HROW  56          // h row stride in dwords (16B-aligned, k 51..55 zero)

// ---- LDS layout (dwords) ----
#define OFF_W1 0
#define OFF_W2 (OFF_W1 + WMAT)          // Wih2
#define OFF_W3 (OFF_W2 + WMAT)          // Whh2
#define OFF_H1 (OFF_W3 + WMAT)          // 31824
#define OFF_H2 (OFF_H1 + MT*HROW)
#define OFF_XB (OFF_H2 + MT*HROW)       // x double buffer [2][16][16]
#define OFF_XC (OFF_XB + 2*MT*16)       // xcur[16] (autoregressive input)
#define OFF_OB (OFF_XC + 16)            // out staging [16][16]
#define TOT_F  (OFF_OB + MT*16 + 16)    // 34416 dwords = 137,664 B

__device__ __forceinline__ float sigm(float v)  { return 1.f / (1.f + __expf(-v)); }
__device__ __forceinline__ float tanh_f(float v){ return 1.f - 2.f / (1.f + __expf(2.f * v)); }

__launch_bounds__(NTH, 1)
__global__ void lstm_seq_kernel(const float* __restrict__ x,
                                const float* __restrict__ Wih1,
                                const float* __restrict__ Whh1,
                                const float* __restrict__ bih1,
                                const float* __restrict__ bhh1,
                                const float* __restrict__ Wih2,
                                const float* __restrict__ Whh2,
                                const float* __restrict__ bih2,
                                const float* __restrict__ bhh2,
                                const float* __restrict__ Wlin,
                                const float* __restrict__ blin,
                                float* __restrict__ out)
{
  extern __shared__ float sm[];
  const int tid  = threadIdx.x;
  const int lane = tid & 63;
  const int wv   = tid >> 6;        // 0 or 1: owns rows wv*8 .. wv*8+7
  const int r0   = wv * 8;
  const int bg0  = blockIdx.x * MT;
  const bool valid = (lane < HH);
  const int j = valid ? lane : 0;   // hidden-unit index for this lane

  // ---- one-time staging ----
  // zero h/x/out regions (also the k>=51 pads, which must stay 0 forever)
  for (int i = OFF_H1 + tid; i < TOT_F; i += NTH) sm[i] = 0.f;
  // weights: dst[c][g][jj][kk] = W[(g*51+jj)][4c+kk]  (0 when 4c+kk >= 51)
  {
    const float* srcs[3] = { Whh1, Wih2, Whh2 };
    #pragma unroll 1
    for (int m = 0; m < 3; ++m) {
      const float* Wsrc = srcs[m];
      const int base = m * WMAT;
      #pragma unroll 1
      for (int i = tid; i < NC * 4 * HH; i += NTH) {
        const int c  = i / (4 * HH);
        const int rm = i - c * 4 * HH;
        const int g  = rm / HH;
        const int jj = rm - g * HH;
        #pragma unroll
        for (int kk = 0; kk < 4; ++kk) {
          const int k = 4 * c + kk;
          sm[base + ((c * 4 + g) * HH + jj) * 4 + kk] =
              (k < HH) ? Wsrc[(g * HH + jj) * HH + k] : 0.f;
        }
      }
    }
  }
  // x chunk 0: wave-local rows (8 rows x 16 steps; 2 dwords/lane)
  #pragma unroll
  for (int p = 0; p < 2; ++p) {
    const int idx = lane + 64 * p;          // 0..127
    const int rl = idx >> 4, tt = idx & 15;
    sm[OFF_XB + (r0 + rl) * 16 + tt] = x[(size_t)(bg0 + r0 + rl) * T_SEQ + tt];
  }
  __syncthreads();

  // per-lane constants (loaded once from global)
  float wi[4], cb1[4], cb2[4];
  #pragma unroll
  for (int g = 0; g < 4; ++g) {
    wi[g]  = valid ? Wih1[g * HH + j] : 0.f;
    cb1[g] = valid ? (bih1[g * HH + j] + bhh1[g * HH + j]) : 0.f;
    cb2[g] = valid ? (bih2[g * HH + j] + bhh2[g * HH + j]) : 0.f;
  }
  const float wl = valid ? Wlin[j] : 0.f;
  const float bl = blin[0];

  float c1[8], c2[8];
  #pragma unroll
  for (int rl = 0; rl < 8; ++rl) { c1[rl] = 0.f; c2[rl] = 0.f; }

  const int h1b = OFF_H1 + r0 * HROW;   // this wave's h rows
  const int h2b = OFF_H2 + r0 * HROW;

  #pragma unroll 1
  for (int t = 0; t < T_TOT; ++t) {
    // prefetch next 16-step x chunk (wave-local rows; in-order LDS => no sync)
    if ((t & 15) == 0 && t < T_SEQ - 16) {
      const int nt = t + 16;
      const int dbuf = ((nt >> 4) & 1) * 256;
      #pragma unroll
      for (int p = 0; p < 2; ++p) {
        const int idx = lane + 64 * p;
        const int rl = idx >> 4, tt = idx & 15;
        sm[OFF_XB + dbuf + (r0 + rl) * 16 + tt] =
            x[(size_t)(bg0 + r0 + rl) * T_SEQ + nt + tt];
      }
    }

    // ---- layer-1 gates: acc[g][rl] = cb1 + wi*x_r + Whh1 @ h1_old ----
    float acc[4][8];
    {
      const bool seq = (t < T_SEQ);
      const int xoff = seq ? (OFF_XB + ((t >> 4) & 1) * 256 + r0 * 16 + (t & 15)) : (OFF_XC + r0);
      const int xstr = seq ? 16 : 1;
      #pragma unroll
      for (int rl = 0; rl < 8; ++rl) {
        const float xv = sm[xoff + rl * xstr];
        #pragma unroll
        for (int g = 0; g < 4; ++g) acc[g][rl] = cb1[g] + wi[g] * xv;
      }
    }
    #pragma unroll 2
    for (int c = 0; c < NC; ++c) {
      float4 wg[4];
      #pragma unroll
      for (int g = 0; g < 4; ++g)
        wg[g] = *reinterpret_cast<const float4*>(&sm[OFF_W1 + ((c * 4 + g) * HH + j) * 4]);
      #pragma unroll
      for (int rl = 0; rl < 8; ++rl) {
        const float4 hv = *reinterpret_cast<const float4*>(&sm[h1b + rl * HROW + c * 4]);
        #pragma unroll
        for (int g = 0; g < 4; ++g)
          acc[g][rl] += wg[g].x * hv.x + wg[g].y * hv.y + wg[g].z * hv.z + wg[g].w * hv.w;
      }
    }
    // ---- layer-1 activations -> h1 (LDS), c1 (regs) ----
    if (valid) {
      #pragma unroll
      for (int rl = 0; rl < 8; ++rl) {
        const float cn = sigm(acc[1][rl]) * c1[rl] + sigm(acc[0][rl]) * tanh_f(acc[2][rl]);
        c1[rl] = cn;
        sm[h1b + rl * HROW + j] = sigm(acc[3][rl]) * tanh_f(cn);
      }
    }

    // ---- layer-2 gates: cb2 + Wih2 @ h1_new + Whh2 @ h2_old ----
    #pragma unroll
    for (int rl = 0; rl < 8; ++rl)
      #pragma unroll
      for (int g = 0; g < 4; ++g) acc[g][rl] = cb2[g];
    #pragma unroll 2
    for (int c = 0; c < NC; ++c) {
      float4 wg[4];
      #pragma unroll
      for (int g = 0; g < 4; ++g)
        wg[g] = *reinterpret_cast<const float4*>(&sm[OFF_W2 + ((c * 4 + g) * HH + j) * 4]);
      #pragma unroll
      for (int rl = 0; rl < 8; ++rl) {
        const float4 hv = *reinterpret_cast<const float4*>(&sm[h1b + rl * HROW + c * 4]);
        #pragma unroll
        for (int g = 0; g < 4; ++g)
          acc[g][rl] += wg[g].x * hv.x + wg[g].y * hv.y + wg[g].z * hv.z + wg[g].w * hv.w;
      }
    }
    #pragma unroll 2
    for (int c = 0; c < NC; ++c) {
      float4 wg[4];
      #pragma unroll
      for (int g = 0; g < 4; ++g)
        wg[g] = *reinterpret_cast<const float4*>(&sm[OFF_W3 + ((c * 4 + g) * HH + j) * 4]);
      #pragma unroll
      for (int rl = 0; rl < 8; ++rl) {
        const float4 hv = *reinterpret_cast<const float4*>(&sm[h2b + rl * HROW + c * 4]);
        #pragma unroll
        for (int g = 0; g < 4; ++g)
          acc[g][rl] += wg[g].x * hv.x + wg[g].y * hv.y + wg[g].z * hv.z + wg[g].w * hv.w;
      }
    }
    // ---- layer-2 activations, output, autoregressive feed ----
    #pragma unroll
    for (int rl = 0; rl < 8; ++rl) {
      float h2v = 0.f;
      if (valid) {
        const float cn = sigm(acc[1][rl]) * c2[rl] + sigm(acc[0][rl]) * tanh_f(acc[2][rl]);
        c2[rl] = cn;
        h2v = sigm(acc[3][rl]) * tanh_f(cn);
        sm[h2b + rl * HROW + j] = h2v;
      }
      float po = wl * h2v;
      #pragma unroll
      for (int m = 32; m >= 1; m >>= 1) po += __shfl_xor(po, m, 64);
      if (lane == 0) {
        const float ov = po + bl;
        sm[OFF_OB + (r0 + rl) * 16 + (t & 15)] = ov;
        sm[OFF_XC + r0 + rl] = ov;
      }
    }
    // flush 16 output columns (coalesced) every 16 steps
    if ((t & 15) == 15) {
      const int tb = t - 15;
      #pragma unroll
      for (int p = 0; p < 2; ++p) {
        const int idx = lane + 64 * p;
        const int rl = idx >> 4, tt = idx & 15;
        out[(size_t)(bg0 + r0 + rl) * T_TOT + tb + tt] = sm[OFF_OB + (r0 + rl) * 16 + tt];
      }
    }
  }
}

extern "C" void kernel_launch(void* const* d_in, const int* in_sizes, int n_in,
                              void* d_out, int out_size, void* d_ws, size_t ws_size,
                              hipStream_t stream) {
  const float* x    = (const float*)d_in[0];
  const float* Wih1 = (const float*)d_in[1];
  const float* Whh1 = (const float*)d_in[2];
  const float* bih1 = (const float*)d_in[3];
  const float* bhh1 = (const float*)d_in[4];
  const float* Wih2 = (const float*)d_in[5];
  const float* Whh2 = (const float*)d_in[6];
  const float* bih2 = (const float*)d_in[7];
  const float* bhh2 = (const float*)d_in[8];
  const float* Wlin = (const float*)d_in[9];
  const float* blin = (const float*)d_in[10];
  float* out = (float*)d_out;

  const size_t smem = (size_t)TOT_F * sizeof(float);  // 137.7 KiB
  (void)hipFuncSetAttribute((const void*)lstm_seq_kernel,
                            hipFuncAttributeMaxDynamicSharedMemorySize, (int)smem);

  lstm_seq_kernel<<<B_TOT / MT, NTH, smem, stream>>>(
      x, Wih1, Whh1, bih1, bhh1, Wih2, Whh2, bih2, bhh2, Wlin, blin, out);
}

// Round 4
// 12727.457 us; speedup vs baseline: 6.4181x; 2.0219x over previous
//
#include <hip/hip_runtime.h>

#define HH    51
#define T_SEQ 1024
#define T_TOT 1088
#define B_TOT 4096
#define MT    16
#define NTH   512

// ---- LDS layout (dwords) ----
#define P1O 0                    // layer-1 gate partials [4][16][64]
#define P2O (P1O + 4*16*64)      // layer-2 gate partials [8][16][64] (m*4+g)
#define H1O (P2O + 8*16*64)      // h1 [16][64] (cols 51..63 stay 0)
#define H2O (H1O + 16*64)        // h2 [16][64]
#define XBO (H2O + 16*64)        // x double buffer [2][16][16]
#define OBO (XBO + 2*16*16)      // out staging [16][16]
#define XCO (OBO + 16*16)        // autoregressive x [16]
#define TOTF (XCO + 32)          // 15152 dw = 60,608 B

__device__ __forceinline__ float sigm(float v)  { return 1.f / (1.f + __expf(-v)); }
__device__ __forceinline__ float tanh_f(float v){ return 1.f - 2.f / (1.f + __expf(2.f * v)); }

__launch_bounds__(NTH, 1)
__global__ void lstm_seq_kernel(const float* __restrict__ x,
                                const float* __restrict__ Wih1,
                                const float* __restrict__ Whh1,
                                const float* __restrict__ bih1,
                                const float* __restrict__ bhh1,
                                const float* __restrict__ Wih2,
                                const float* __restrict__ Whh2,
                                const float* __restrict__ bih2,
                                const float* __restrict__ bhh2,
                                const float* __restrict__ Wlin,
                                const float* __restrict__ blin,
                                float* __restrict__ out)
{
  extern __shared__ float sm[];
  const int tid  = threadIdx.x;
  const int lane = tid & 63;
  const int w    = tid >> 6;          // wave 0..7
  const int bg0  = blockIdx.x * MT;
  const bool jv  = (lane < HH);
  const int  j   = lane;

  // zero LDS (h1/h2 init + pad columns must be 0)
  for (int i = tid; i < TOTF; i += NTH) sm[i] = 0.f;

  // ---- per-wave work assignment ----
  const int gA  = w & 3;              // A: layer-1 gate
  const int rA0 = (w >> 2) * 8;       // A: 8-row half
  const int mC  = (w >> 2) & 1;       // C: 0 = Wih2@h1_new, 1 = Whh2@h2_old
  const int gC  = w & 3;              // C: layer-2 gate
  const int rB0 = 2 * w;              // B/D: rows 2w, 2w+1

  // ---- register-resident weights (fully unrolled: no runtime indexing) ----
  float WA[52];                       // Whh1[gA*51+j][k], k-padded
  #pragma unroll
  for (int k = 0; k < 52; ++k)
    WA[k] = (jv && k < HH) ? Whh1[(gA * HH + j) * HH + k] : 0.f;
  const float wiA = jv ? Wih1[gA * HH + j] : 0.f;
  const float cbA = jv ? (bih1[gA * HH + j] + bhh1[gA * HH + j]) : 0.f;

  const float* MC = mC ? Whh2 : Wih2;
  float WCr[52];                      // (Wih2|Whh2)[gC*51+j][k]
  #pragma unroll
  for (int k = 0; k < 52; ++k)
    WCr[k] = (jv && k < HH) ? MC[(gC * HH + j) * HH + k] : 0.f;
  const float cbC = (jv && mC == 0) ? (bih2[gC * HH + j] + bhh2[gC * HH + j]) : 0.f;

  const float wl = jv ? Wlin[j] : 0.f;
  const float bl = blin[0];

  // x chunk 0 (16 rows x 16 steps; waves 0-3)
  if (w < 4) {
    const int idx = w * 64 + lane;    // 0..255
    const int r = idx >> 4, tt = idx & 15;
    sm[XBO + r * 16 + tt] = x[(size_t)(bg0 + r) * T_SEQ + tt];
  }

  float c1[2] = {0.f, 0.f};
  float c2[2] = {0.f, 0.f};
  __syncthreads();

  #pragma unroll 1
  for (int t = 0; t < T_TOT; ++t) {
    // prefetch next x chunk into other buffer half (waves 0-3)
    if ((t & 15) == 0 && (t + 16) < T_SEQ && w < 4) {
      const int nt = t + 16;
      const int idx = w * 64 + lane;
      const int r = idx >> 4, tt = idx & 15;
      sm[XBO + ((nt >> 4) & 1) * 256 + r * 16 + tt] =
          x[(size_t)(bg0 + r) * T_SEQ + nt + tt];
    }

    // ---- A: layer-1 gate gA for rows rA0..rA0+7 ----
    {
      float acc[8];
      #pragma unroll
      for (int ri = 0; ri < 8; ++ri) {
        const int r = rA0 + ri;
        const float xv = (t < T_SEQ)
            ? sm[XBO + ((t >> 4) & 1) * 256 + r * 16 + (t & 15)]
            : sm[XCO + r];
        acc[ri] = cbA + wiA * xv;
      }
      #pragma unroll
      for (int c = 0; c < 13; ++c) {
        #pragma unroll
        for (int ri = 0; ri < 8; ++ri) {
          const float4 hv = *reinterpret_cast<const float4*>(&sm[H1O + (rA0 + ri) * 64 + 4 * c]);
          acc[ri] += WA[4*c+0] * hv.x + WA[4*c+1] * hv.y + WA[4*c+2] * hv.z + WA[4*c+3] * hv.w;
        }
      }
      #pragma unroll
      for (int ri = 0; ri < 8; ++ri)
        sm[P1O + (gA * 16 + rA0 + ri) * 64 + j] = acc[ri];
    }
    __syncthreads();

    // ---- B: act1 for rows 2w, 2w+1 ----
    #pragma unroll
    for (int rr = 0; rr < 2; ++rr) {
      const int r = rB0 + rr;
      const float g0 = sm[P1O + (0 * 16 + r) * 64 + j];
      const float g1 = sm[P1O + (1 * 16 + r) * 64 + j];
      const float g2 = sm[P1O + (2 * 16 + r) * 64 + j];
      const float g3 = sm[P1O + (3 * 16 + r) * 64 + j];
      const float cn = sigm(g1) * c1[rr] + sigm(g0) * tanh_f(g2);
      c1[rr] = cn;
      sm[H1O + r * 64 + j] = sigm(g3) * tanh_f(cn);   // lanes>=51 write 0
    }
    __syncthreads();

    // ---- C: layer-2 partial (mC, gate gC) for all 16 rows ----
    {
      float acc[16];
      #pragma unroll
      for (int ri = 0; ri < 16; ++ri) acc[ri] = cbC;
      const int hb = mC ? H2O : H1O;
      #pragma unroll
      for (int c = 0; c < 13; ++c) {
        #pragma unroll
        for (int ri = 0; ri < 16; ++ri) {
          const float4 hv = *reinterpret_cast<const float4*>(&sm[hb + ri * 64 + 4 * c]);
          acc[ri] += WCr[4*c+0] * hv.x + WCr[4*c+1] * hv.y + WCr[4*c+2] * hv.z + WCr[4*c+3] * hv.w;
        }
      }
      #pragma unroll
      for (int ri = 0; ri < 16; ++ri)
        sm[P2O + ((mC * 4 + gC) * 16 + ri) * 64 + j] = acc[ri];
    }
    __syncthreads();

    // ---- D: act2, linear out, autoregressive feed (rows 2w, 2w+1) ----
    #pragma unroll
    for (int rr = 0; rr < 2; ++rr) {
      const int r = rB0 + rr;
      float p[4];
      #pragma unroll
      for (int g = 0; g < 4; ++g)
        p[g] = sm[P2O + (g * 16 + r) * 64 + j] + sm[P2O + ((4 + g) * 16 + r) * 64 + j];
      const float cn = sigm(p[1]) * c2[rr] + sigm(p[0]) * tanh_f(p[2]);
      c2[rr] = cn;
      const float h2 = sigm(p[3]) * tanh_f(cn);
      sm[H2O + r * 64 + j] = h2;                       // lanes>=51 write 0
      float po = wl * h2;
      #pragma unroll
      for (int m = 32; m >= 1; m >>= 1) po += __shfl_xor(po, m, 64);
      if (lane == 0) {
        const float ov = po + bl;
        sm[OBO + r * 16 + (t & 15)] = ov;
        sm[XCO + r] = ov;                              // next-step x when t>=1024
      }
    }
    // flush out staging every 16 steps (rows 2w,2w+1; lanes 0..31)
    if ((t & 15) == 15 && lane < 32) {
      const int rr = lane >> 4, tt = lane & 15;
      out[(size_t)(bg0 + rB0 + rr) * T_TOT + (t - 15) + tt] =
          sm[OBO + (rB0 + rr) * 16 + tt];
    }
    __syncthreads();
  }
}

extern "C" void kernel_launch(void* const* d_in, const int* in_sizes, int n_in,
                              void* d_out, int out_size, void* d_ws, size_t ws_size,
                              hipStream_t stream) {
  const float* x    = (const float*)d_in[0];
  const float* Wih1 = (const float*)d_in[1];
  const float* Whh1 = (const float*)d_in[2];
  const float* bih1 = (const float*)d_in[3];
  const float* bhh1 = (const float*)d_in[4];
  const float* Wih2 = (const float*)d_in[5];
  const float* Whh2 = (const float*)d_in[6];
  const float* bih2 = (const float*)d_in[7];
  const float* bhh2 = (const float*)d_in[8];
  const float* Wlin = (const float*)d_in[9];
  const float* blin = (const float*)d_in[10];
  float* out = (float*)d_out;

  const size_t smem = (size_t)TOTF * sizeof(float);   // 60.6 KiB
  (void)hipFuncSetAttribute((const void*)lstm_seq_kernel,
                            hipFuncAttributeMaxDynamicSharedMemorySize, (int)smem);

  lstm_seq_kernel<<<B_TOT / MT, NTH, smem, stream>>>(
      x, Wih1, Whh1, bih1, bhh1, Wih2, Whh2, bih2, bhh2, Wlin, blin, out);
}